// Round 15
// baseline (301.745 us; speedup 1.0000x reference)
//
#include <hip/hip_runtime.h>
#include <cstdint>

// Problem constants (from reference setup_inputs): B=256, IN=1024, OUT=1024.
#define BATCH 256
#define INF   1024
#define OUTF  1024

// ---------------------------------------------------------------------------
// Decode helper: 32 pulse floats (index 0 = MSB) -> uint32 bit pattern.
// p4 points at the value's 8 contiguous float4s (128 B).
// ---------------------------------------------------------------------------
__device__ __forceinline__ uint32_t assemble_bits(const float4* __restrict__ p4) {
    uint32_t u = 0;
#pragma unroll
    for (int j = 0; j < 8; ++j) {
        float4 v = p4[j];
        int sh = 31 - j * 4;  // pulse index j*4 -> bit (31 - j*4)
        u |= (v.x > 0.5f ? 1u : 0u) << sh;
        u |= (v.y > 0.5f ? 1u : 0u) << (sh - 1);
        u |= (v.z > 0.5f ? 1u : 0u) << (sh - 2);
        u |= (v.w > 0.5f ? 1u : 0u) << (sh - 3);
    }
    return u;
}

// Streaming decode (x AND w): thread i reads its own 128 B, writes 1 float.
__global__ __launch_bounds__(256) void decode_pulses(
    const float* __restrict__ pulses, float* __restrict__ out, int n) {
    int i = blockIdx.x * blockDim.x + threadIdx.x;
    if (i >= n) return;
    const float4* p4 = reinterpret_cast<const float4*>(pulses) + (size_t)i * 8;
    out[i] = __uint_as_float(assemble_bits(p4));
}

// ---------------------------------------------------------------------------
// GEMM with strict left-to-right FP32 accumulation + pulse re-encode.
// Block (64,4) = 256 threads, covers 64 o x 8 b (BQ=2 per thread).
//
// v3 structure (from the LDS-pipe cost model):
//  - x is NOT staged in LDS. Each wave's x addresses are uniform across all
//    64 lanes -> one coalesced L1/L2 request per load on the VMEM pipe.
//    (In LDS this was a 64-way broadcast duplication: 512 KB/wave read for
//    8 KB of distinct data — ~half the LDS pipe time.)
//  - w_s is [o][k] so each lane reads ITS OWN row as ds_read_b128 (b128 is
//    ~2x the LDS bytes/cyc of b32). Without swizzle all 64 lanes' quads land
//    on the same 4 banks (row stride 256 B); XOR-16 granule swizzle
//    (g' = k4 ^ (o&15), same involution on write and read) spreads them
//    across all 32 banks.
//  - Register double-buffer (r14's win): tile kt+1's 64 B-contiguous global
//    loads issue before tile kt's compute; LDS writes land after the barrier.
//
// fp contract(off): hipcc defaults to -ffp-contract=fast-honor-pragmas; a
// fused v_fmac skips product rounding and breaks bit-exactness vs the
// reference's round(mul) -> round(add) sequence.
// ---------------------------------------------------------------------------
__global__ __launch_bounds__(256) void gemm_encode(
    const float* __restrict__ xf,   // [BATCH][INF]
    const float* __restrict__ wf,   // [OUTF][INF] (row-major decoded)
    float* __restrict__ out)        // [BATCH][OUTF][32]
{
#pragma clang fp contract(off)
    __shared__ float w_s[64 * 64];      // [o][16 granules of 4 floats], swizzled
    const int tx = threadIdx.x, ty = threadIdx.y;
    const int t  = ty * 64 + tx;        // 0..255
    const int o0 = blockIdx.x * 64;
    const int b0 = blockIdx.y * 8;

    // staging role: o-row = t&63, granule base = (t>>6)*4 (64 B contiguous)
    const int o_loc = t & 63;
    const int g0    = (t >> 6) * 4;     // granules g0..g0+3
    const int swz   = o_loc & 15;
    const float* __restrict__ wbase = wf + (size_t)(o0 + o_loc) * INF;

    // x rows for this wave (addresses uniform across the wave's 64 lanes)
    const float* __restrict__ xra = xf + (size_t)(b0 + 2 * ty) * INF;
    const float* __restrict__ xrb = xra + INF;

    float4 wreg[4];

    // ---- prologue: stage w tile 0 ----
#pragma unroll
    for (int h = 0; h < 4; ++h)
        wreg[h] = *reinterpret_cast<const float4*>(wbase + (g0 + h) * 4);
#pragma unroll
    for (int h = 0; h < 4; ++h) {
        const int gs = (g0 + h) ^ swz;
        *reinterpret_cast<float4*>(&w_s[o_loc * 64 + gs * 4]) = wreg[h];
    }
    __syncthreads();

    float acc0 = 0.0f, acc1 = 0.0f;
    const int rswz = tx & 15;           // read-side swizzle (own row = tx)

    for (int kt = 0; kt < 16; ++kt) {
        // ---- prefetch w tile kt+1 into registers ----
        if (kt < 15) {
            const int k0 = (kt + 1) * 64;
#pragma unroll
            for (int h = 0; h < 4; ++h)
                wreg[h] = *reinterpret_cast<const float4*>(wbase + k0 + (g0 + h) * 4);
        }

        // ---- compute tile kt: w from LDS (b128 swizzled), x from global ----
        const float* xpa = xra + kt * 64;
        const float* xpb = xrb + kt * 64;
#pragma unroll
        for (int k4 = 0; k4 < 16; ++k4) {
            float4 w = *reinterpret_cast<const float4*>(
                &w_s[tx * 64 + ((k4 ^ rswz) * 4)]);
            float4 a = *reinterpret_cast<const float4*>(xpa + k4 * 4);
            float4 b = *reinterpret_cast<const float4*>(xpb + k4 * 4);
            // strictly ascending k within each independent output chain
            acc0 = acc0 + a.x * w.x;
            acc0 = acc0 + a.y * w.y;
            acc0 = acc0 + a.z * w.z;
            acc0 = acc0 + a.w * w.w;
            acc1 = acc1 + b.x * w.x;
            acc1 = acc1 + b.y * w.y;
            acc1 = acc1 + b.z * w.z;
            acc1 = acc1 + b.w * w.w;
        }
        __syncthreads();   // all compute on tile kt done before overwrite

        // ---- write prefetched tile kt+1 to LDS ----
        if (kt < 15) {
#pragma unroll
            for (int h = 0; h < 4; ++h) {
                const int gs = (g0 + h) ^ swz;
                *reinterpret_cast<float4*>(&w_s[o_loc * 64 + gs * 4]) = wreg[h];
            }
            __syncthreads();   // tile kt+1 visible before next compute
        }
    }

    // Re-encode both results to pulse bits (plain cached stores: L2 merges
    // the 16 B partials into full lines -> exactly 32 MB HBM writes).
    const int o = o0 + tx;
    float accs[2] = {acc0, acc1};
#pragma unroll
    for (int q = 0; q < 2; ++q) {
        uint32_t u = __float_as_uint(accs[q]);
        float4* dst = reinterpret_cast<float4*>(out)
                      + ((size_t)(b0 + ty * 2 + q) * OUTF + o) * 8;
#pragma unroll
        for (int j = 0; j < 8; ++j) {
            int sh = 31 - j * 4;
            dst[j] = make_float4((float)((u >> sh) & 1u),
                                 (float)((u >> (sh - 1)) & 1u),
                                 (float)((u >> (sh - 2)) & 1u),
                                 (float)((u >> (sh - 3)) & 1u));
        }
    }
}

extern "C" void kernel_launch(void* const* d_in, const int* in_sizes, int n_in,
                              void* d_out, int out_size, void* d_ws, size_t ws_size,
                              hipStream_t stream) {
    const float* x_pulses = (const float*)d_in[0];   // [256][1024][32]
    const float* w_pulses = (const float*)d_in[1];   // [1024][1024][32]
    float* out = (float*)d_out;                      // [256][1024][32]

    float* xf = (float*)d_ws;                        // 256*1024 floats  (1 MB)
    float* wf = xf + (size_t)BATCH * INF;            // 1024*1024 floats (4 MB)

    // 1) decode x -> xf [B][IN]
    {
        int n = BATCH * INF;                         // 262144
        decode_pulses<<<(n + 255) / 256, 256, 0, stream>>>(x_pulses, xf, n);
    }
    // 2) decode w -> wf [OUT][IN] (row-major streaming, no transpose)
    {
        int n = OUTF * INF;                          // 1048576
        decode_pulses<<<n / 256, 256, 0, stream>>>(w_pulses, wf, n);
    }
    // 3) GEMM + encode (w-only LDS w/ XOR swizzle, x uniform from global)
    {
        dim3 grid(OUTF / 64, BATCH / 8);             // (16, 32)
        dim3 block(64, 4);
        gemm_encode<<<grid, block, 0, stream>>>(xf, wf, out);
    }
}

// Round 16
// 272.074 us; speedup vs baseline: 1.1091x; 1.1091x over previous
//
#include <hip/hip_runtime.h>
#include <cstdint>

// Problem constants (from reference setup_inputs): B=256, IN=1024, OUT=1024.
#define BATCH 256
#define INF   1024
#define OUTF  1024

// ---------------------------------------------------------------------------
// Decode helper: 32 pulse floats (index 0 = MSB) -> uint32 bit pattern.
// ---------------------------------------------------------------------------
__device__ __forceinline__ uint32_t assemble_bits(const float4* __restrict__ p4) {
    uint32_t u = 0;
#pragma unroll
    for (int j = 0; j < 8; ++j) {
        float4 v = p4[j];
        int sh = 31 - j * 4;  // pulse index j*4 -> bit (31 - j*4)
        u |= (v.x > 0.5f ? 1u : 0u) << sh;
        u |= (v.y > 0.5f ? 1u : 0u) << (sh - 1);
        u |= (v.z > 0.5f ? 1u : 0u) << (sh - 2);
        u |= (v.w > 0.5f ? 1u : 0u) << (sh - 3);
    }
    return u;
}

// Streaming decode (x AND w): thread i reads its own 128 B, writes 1 float.
__global__ __launch_bounds__(256) void decode_pulses(
    const float* __restrict__ pulses, float* __restrict__ out, int n) {
    int i = blockIdx.x * blockDim.x + threadIdx.x;
    if (i >= n) return;
    const float4* p4 = reinterpret_cast<const float4*>(pulses) + (size_t)i * 8;
    out[i] = __uint_as_float(assemble_bits(p4));
}

// ---------------------------------------------------------------------------
// GEMM with strict left-to-right FP32 accumulation + pulse re-encode.
// Block (64,4) = 256 threads, covers 64 o x 8 b (BQ=2 per thread).
//
// v4 = r14 structure with the r15-validated w layout, r15's mistake reverted:
//  - w_s[o][k] XOR-16 granule swizzle (gs = g ^ (o&15), same involution on
//    write and read): each lane reads ITS OWN row as ds_read_b128 -> 4x fewer
//    w LDS instructions than b32 column reads; r15 measured 0 bank conflicts.
//  - x IS staged in LDS (r15's x-from-global was latency-bound: VALUBusy 14%,
//    per-k4 vmcnt stalls). Uniform-address float4 broadcast from LDS is
//    ~free in bank bandwidth and ~30 cyc latency.
//  - Register double-buffer (r14's win): tile kt+1's contiguous global loads
//    issue before tile kt's compute; LDS writes land after the barrier.
//
// fp contract(off): hipcc defaults to -ffp-contract=fast-honor-pragmas; a
// fused v_fmac skips product rounding and breaks bit-exactness vs the
// reference's round(mul) -> round(add) sequence.
// ---------------------------------------------------------------------------
__global__ __launch_bounds__(256) void gemm_encode(
    const float* __restrict__ xf,   // [BATCH][INF]
    const float* __restrict__ wf,   // [OUTF][INF] (row-major decoded)
    float* __restrict__ out)        // [BATCH][OUTF][32]
{
#pragma clang fp contract(off)
    __shared__ float w_s[64 * 64];      // [o][16 granules of 4 floats], swizzled
    __shared__ float x_s[8][64];        // [b][k], reads are uniform broadcast
    const int tx = threadIdx.x, ty = threadIdx.y;
    const int t  = ty * 64 + tx;        // 0..255
    const int o0 = blockIdx.x * 64;
    const int b0 = blockIdx.y * 8;

    // w staging role: o-row = t&63, granule base = (t>>6)*4 (64 B contiguous)
    const int o_loc = t & 63;
    const int g0    = (t >> 6) * 4;     // granules g0..g0+3
    const int swz   = o_loc & 15;
    const float* __restrict__ wbase = wf + (size_t)(o0 + o_loc) * INF;
    // x staging role (threads 0..127): row = t>>4, 16 B segment = t&15
    const int xr = t >> 4, xs = t & 15;

    float4 wreg[4];
    float4 xreg;

    // ---- prologue: stage tile 0 ----
#pragma unroll
    for (int h = 0; h < 4; ++h)
        wreg[h] = *reinterpret_cast<const float4*>(wbase + (g0 + h) * 4);
    if (t < 128)
        xreg = *reinterpret_cast<const float4*>(xf + (size_t)(b0 + xr) * INF + xs * 4);
#pragma unroll
    for (int h = 0; h < 4; ++h) {
        const int gs = (g0 + h) ^ swz;
        *reinterpret_cast<float4*>(&w_s[o_loc * 64 + gs * 4]) = wreg[h];
    }
    if (t < 128)
        *reinterpret_cast<float4*>(&x_s[xr][xs * 4]) = xreg;
    __syncthreads();

    float acc0 = 0.0f, acc1 = 0.0f;
    const int rswz = tx & 15;           // read-side swizzle (own row = tx)

    for (int kt = 0; kt < 16; ++kt) {
        // ---- prefetch tile kt+1 into registers (hides under compute) ----
        if (kt < 15) {
            const int k0 = (kt + 1) * 64;
#pragma unroll
            for (int h = 0; h < 4; ++h)
                wreg[h] = *reinterpret_cast<const float4*>(wbase + k0 + (g0 + h) * 4);
            if (t < 128)
                xreg = *reinterpret_cast<const float4*>(xf + (size_t)(b0 + xr) * INF + k0 + xs * 4);
        }

        // ---- compute tile kt: w b128 swizzled (own row), x uniform bcast ----
        const float* xrow0 = x_s[ty * 2];
        const float* xrow1 = x_s[ty * 2 + 1];
#pragma unroll
        for (int k4 = 0; k4 < 16; ++k4) {
            float4 w = *reinterpret_cast<const float4*>(
                &w_s[tx * 64 + ((k4 ^ rswz) * 4)]);
            float4 a = *reinterpret_cast<const float4*>(xrow0 + k4 * 4);
            float4 b = *reinterpret_cast<const float4*>(xrow1 + k4 * 4);
            // strictly ascending k within each independent output chain
            acc0 = acc0 + a.x * w.x;
            acc0 = acc0 + a.y * w.y;
            acc0 = acc0 + a.z * w.z;
            acc0 = acc0 + a.w * w.w;
            acc1 = acc1 + b.x * w.x;
            acc1 = acc1 + b.y * w.y;
            acc1 = acc1 + b.z * w.z;
            acc1 = acc1 + b.w * w.w;
        }
        __syncthreads();   // all compute on tile kt done before overwrite

        // ---- write prefetched tile kt+1 to LDS ----
        if (kt < 15) {
#pragma unroll
            for (int h = 0; h < 4; ++h) {
                const int gs = (g0 + h) ^ swz;
                *reinterpret_cast<float4*>(&w_s[o_loc * 64 + gs * 4]) = wreg[h];
            }
            if (t < 128)
                *reinterpret_cast<float4*>(&x_s[xr][xs * 4]) = xreg;
            __syncthreads();   // tile kt+1 visible before next compute
        }
    }

    // Re-encode both results to pulse bits (plain cached stores: L2 merges
    // the 16 B partials into full lines).
    const int o = o0 + tx;
    float accs[2] = {acc0, acc1};
#pragma unroll
    for (int q = 0; q < 2; ++q) {
        uint32_t u = __float_as_uint(accs[q]);
        float4* dst = reinterpret_cast<float4*>(out)
                      + ((size_t)(b0 + ty * 2 + q) * OUTF + o) * 8;
#pragma unroll
        for (int j = 0; j < 8; ++j) {
            int sh = 31 - j * 4;
            dst[j] = make_float4((float)((u >> sh) & 1u),
                                 (float)((u >> (sh - 1)) & 1u),
                                 (float)((u >> (sh - 2)) & 1u),
                                 (float)((u >> (sh - 3)) & 1u));
        }
    }
}

extern "C" void kernel_launch(void* const* d_in, const int* in_sizes, int n_in,
                              void* d_out, int out_size, void* d_ws, size_t ws_size,
                              hipStream_t stream) {
    const float* x_pulses = (const float*)d_in[0];   // [256][1024][32]
    const float* w_pulses = (const float*)d_in[1];   // [1024][1024][32]
    float* out = (float*)d_out;                      // [256][1024][32]

    float* xf = (float*)d_ws;                        // 256*1024 floats  (1 MB)
    float* wf = xf + (size_t)BATCH * INF;            // 1024*1024 floats (4 MB)

    // 1) decode x -> xf [B][IN]
    {
        int n = BATCH * INF;                         // 262144
        decode_pulses<<<(n + 255) / 256, 256, 0, stream>>>(x_pulses, xf, n);
    }
    // 2) decode w -> wf [OUT][IN] (row-major streaming, no transpose)
    {
        int n = OUTF * INF;                          // 1048576
        decode_pulses<<<n / 256, 256, 0, stream>>>(w_pulses, wf, n);
    }
    // 3) GEMM + encode (w b128 swizzled LDS + x LDS broadcast, BQ=2)
    {
        dim3 grid(OUTF / 64, BATCH / 8);             // (16, 32)
        dim3 block(64, 4);
        gemm_encode<<<grid, block, 0, stream>>>(xf, wf, out);
    }
}

// Round 18
// 268.817 us; speedup vs baseline: 1.1225x; 1.0121x over previous
//
#include <hip/hip_runtime.h>
#include <cstdint>

// Problem constants (from reference setup_inputs): B=256, IN=1024, OUT=1024.
#define BATCH 256
#define INF   1024
#define OUTF  1024

#define WSTRIDE 68   // w_s row stride in floats: 272 B = 16B-aligned, and
                     // 68 mod 32(banks) = 4 -> b128 row reads are 2-way (free)

// ---------------------------------------------------------------------------
// Decode helper: 32 pulse floats (index 0 = MSB) -> uint32 bit pattern.
// ---------------------------------------------------------------------------
__device__ __forceinline__ uint32_t assemble_bits(const float4* __restrict__ p4) {
    uint32_t u = 0;
#pragma unroll
    for (int j = 0; j < 8; ++j) {
        float4 v = p4[j];
        int sh = 31 - j * 4;  // pulse index j*4 -> bit (31 - j*4)
        u |= (v.x > 0.5f ? 1u : 0u) << sh;
        u |= (v.y > 0.5f ? 1u : 0u) << (sh - 1);
        u |= (v.z > 0.5f ? 1u : 0u) << (sh - 2);
        u |= (v.w > 0.5f ? 1u : 0u) << (sh - 3);
    }
    return u;
}

// Streaming decode (x AND w): thread i reads its own 128 B, writes 1 float.
__global__ __launch_bounds__(256) void decode_pulses(
    const float* __restrict__ pulses, float* __restrict__ out, int n) {
    int i = blockIdx.x * blockDim.x + threadIdx.x;
    if (i >= n) return;
    const float4* p4 = reinterpret_cast<const float4*>(pulses) + (size_t)i * 8;
    out[i] = __uint_as_float(assemble_bits(p4));
}

// ---------------------------------------------------------------------------
// GEMM with strict left-to-right FP32 accumulation + pulse re-encode.
// Block (64,4) = 256 threads, covers 64 o x 8 b (BQ=2 per thread).
//
// v5 = r14 structure + two transaction-count fixes (r16 post-mortem):
//  - w_s[64][WSTRIDE=68]: lane tx reads ITS OWN row as ds_read_b128 with a
//    constant base VGPR + IMMEDIATE offset k4*16 (no per-read VALU address
//    math -- r16's XOR swizzle defeated offset folding and regressed).
//    Pad-68 makes row b128 reads 2-way bank-aliased = free (m136).
//  - Coalesced w staging: each 16-lane run loads consecutive 16 B granules
//    of ONE o-row (4 x 256 B runs per instruction) instead of 64 lanes
//    striding 4 KB (64 L2 lines per instruction).
//  - x staged in LDS, read as uniform-address float4 broadcast (free); x
//    from global was r15's latency-bound mistake (VALUBusy 14%).
//  - Register double-buffer (r14's win): tile kt+1's global loads issue
//    before tile kt's compute; LDS writes land between the two barriers.
//
// fp contract(off): hipcc defaults to -ffp-contract=fast-honor-pragmas; a
// fused v_fmac skips product rounding and breaks bit-exactness vs the
// reference's round(mul) -> round(add) sequence.
// ---------------------------------------------------------------------------
__global__ __launch_bounds__(256) void gemm_encode(
    const float* __restrict__ xf,   // [BATCH][INF]
    const float* __restrict__ wf,   // [OUTF][INF] (row-major decoded)
    float* __restrict__ out)        // [BATCH][OUTF][32]
{
#pragma clang fp contract(off)
    __shared__ float w_s[64 * WSTRIDE];  // [o][k granules], pad-68 rows
    __shared__ float x_s[8][64];         // [b][k], reads are uniform broadcast
    const int tx = threadIdx.x, ty = threadIdx.y;
    const int t  = ty * 64 + tx;         // 0..255
    const int o0 = blockIdx.x * 64;
    const int b0 = blockIdx.y * 8;

    // w staging role (coalesced): lane l, wave wv. Instruction h loads
    // granule (l&15) of o-row  wv*16 + (l>>4) + 4*h  -> 4 contiguous 256 B
    // runs per instruction.
    const int l  = t & 63;
    const int wv = t >> 6;
    const int og = wv * 16 + (l >> 4);   // o-row base for h=0
    const int gr = l & 15;               // granule (16 B) index
    // x staging role (threads 0..127): row = t>>4, 16 B segment = t&15
    const int xr = t >> 4, xs = t & 15;

    float4 wreg[4];
    float4 xreg;

    // ---- prologue: stage tile 0 ----
#pragma unroll
    for (int h = 0; h < 4; ++h)
        wreg[h] = *reinterpret_cast<const float4*>(
            wf + (size_t)(o0 + og + 4 * h) * INF + gr * 4);
    if (t < 128)
        xreg = *reinterpret_cast<const float4*>(xf + (size_t)(b0 + xr) * INF + xs * 4);
#pragma unroll
    for (int h = 0; h < 4; ++h)
        *reinterpret_cast<float4*>(&w_s[(og + 4 * h) * WSTRIDE + gr * 4]) = wreg[h];
    if (t < 128)
        *reinterpret_cast<float4*>(&x_s[xr][xs * 4]) = xreg;
    __syncthreads();

    float acc0 = 0.0f, acc1 = 0.0f;
    const float* __restrict__ wrow = &w_s[tx * WSTRIDE];  // own row, const base

    for (int kt = 0; kt < 16; ++kt) {
        // ---- prefetch tile kt+1 into registers (hides under compute) ----
        if (kt < 15) {
            const int k0 = (kt + 1) * 64;
#pragma unroll
            for (int h = 0; h < 4; ++h)
                wreg[h] = *reinterpret_cast<const float4*>(
                    wf + (size_t)(o0 + og + 4 * h) * INF + k0 + gr * 4);
            if (t < 128)
                xreg = *reinterpret_cast<const float4*>(
                    xf + (size_t)(b0 + xr) * INF + k0 + xs * 4);
        }

        // ---- compute tile kt: w b128 own-row imm-offset, x uniform bcast ----
        const float* xrow0 = x_s[ty * 2];
        const float* xrow1 = x_s[ty * 2 + 1];
#pragma unroll
        for (int k4 = 0; k4 < 16; ++k4) {
            float4 w = *reinterpret_cast<const float4*>(wrow + k4 * 4);
            float4 a = *reinterpret_cast<const float4*>(xrow0 + k4 * 4);
            float4 b = *reinterpret_cast<const float4*>(xrow1 + k4 * 4);
            // strictly ascending k within each independent output chain
            acc0 = acc0 + a.x * w.x;
            acc0 = acc0 + a.y * w.y;
            acc0 = acc0 + a.z * w.z;
            acc0 = acc0 + a.w * w.w;
            acc1 = acc1 + b.x * w.x;
            acc1 = acc1 + b.y * w.y;
            acc1 = acc1 + b.z * w.z;
            acc1 = acc1 + b.w * w.w;
        }
        __syncthreads();   // all compute on tile kt done before overwrite

        // ---- write prefetched tile kt+1 to LDS ----
        if (kt < 15) {
#pragma unroll
            for (int h = 0; h < 4; ++h)
                *reinterpret_cast<float4*>(&w_s[(og + 4 * h) * WSTRIDE + gr * 4]) = wreg[h];
            if (t < 128)
                *reinterpret_cast<float4*>(&x_s[xr][xs * 4]) = xreg;
            __syncthreads();   // tile kt+1 visible before next compute
        }
    }

    // Re-encode both results to pulse bits (plain cached stores: L2 merges
    // the 16 B partials into full lines).
    const int o = o0 + tx;
    float accs[2] = {acc0, acc1};
#pragma unroll
    for (int q = 0; q < 2; ++q) {
        uint32_t u = __float_as_uint(accs[q]);
        float4* dst = reinterpret_cast<float4*>(out)
                      + ((size_t)(b0 + ty * 2 + q) * OUTF + o) * 8;
#pragma unroll
        for (int j = 0; j < 8; ++j) {
            int sh = 31 - j * 4;
            dst[j] = make_float4((float)((u >> sh) & 1u),
                                 (float)((u >> (sh - 1)) & 1u),
                                 (float)((u >> (sh - 2)) & 1u),
                                 (float)((u >> (sh - 3)) & 1u));
        }
    }
}

extern "C" void kernel_launch(void* const* d_in, const int* in_sizes, int n_in,
                              void* d_out, int out_size, void* d_ws, size_t ws_size,
                              hipStream_t stream) {
    const float* x_pulses = (const float*)d_in[0];   // [256][1024][32]
    const float* w_pulses = (const float*)d_in[1];   // [1024][1024][32]
    float* out = (float*)d_out;                      // [256][1024][32]

    float* xf = (float*)d_ws;                        // 256*1024 floats  (1 MB)
    float* wf = xf + (size_t)BATCH * INF;            // 1024*1024 floats (4 MB)

    // 1) decode x -> xf [B][IN]
    {
        int n = BATCH * INF;                         // 262144
        decode_pulses<<<(n + 255) / 256, 256, 0, stream>>>(x_pulses, xf, n);
    }
    // 2) decode w -> wf [OUT][IN] (row-major streaming, no transpose)
    {
        int n = OUTF * INF;                          // 1048576
        decode_pulses<<<n / 256, 256, 0, stream>>>(w_pulses, wf, n);
    }
    // 3) GEMM + encode (pad-68 b128 w reads, coalesced staging, BQ=2)
    {
        dim3 grid(OUTF / 64, BATCH / 8);             // (16, 32)
        dim3 block(64, 4);
        gemm_encode<<<grid, block, 0, stream>>>(xf, wf, out);
    }
}